// Round 12
// baseline (79.968 us; speedup 1.0000x reference)
//
#include <hip/hip_runtime.h>
#include <hip/hip_bf16.h>

// Problem constants
#define XH   64
#define XW   64
#define CIN  256
#define COUT 256
#define BATCH 4
#define KK9  9
#define M_TOT 16384      // BATCH*XH*XW
#define K_TOT 2304       // KK9*CIN
#define NKSTEP 36        // K_TOT/64

typedef __attribute__((ext_vector_type(8))) short short8;
typedef __attribute__((ext_vector_type(4))) short short4v;
typedef __attribute__((ext_vector_type(4))) float f32x4;

// Workspace layout (bytes)
#define OM_OFF   0
#define OM_BYTES (BATCH*27*4096*4)            // 1,769,472
#define XT_OFF   (OM_OFF + OM_BYTES)
#define XT_BYTES (BATCH*4096*CIN*2)           // 8,388,608 (bf16)
#define WT_OFF   (XT_OFF + XT_BYTES)
#define WT_BYTES (COUT*K_TOT*2)               // 1,179,648  ([tk][256o][64j], XOR-pre-swizzled)
#define WOT_OFF  (WT_OFF + WT_BYTES)
#define WOT_BYTES (36*32*64*2)                // 147,456    ([tk][32oc][64j], XOR-pre-swizzled)

__device__ __forceinline__ void async16(const void* g, void* l) {
  __builtin_amdgcn_global_load_lds((const __attribute__((address_space(1))) void*)g,
                                   (__attribute__((address_space(3))) void*)l,
                                   16, 0, 0);
}

__device__ __forceinline__ float b2f(short s) {
  union { float f; unsigned u; } x;
  x.u = ((unsigned)(unsigned short)s) << 16;
  return x.f;
}

struct Taps { short8 t00, t01, t10, t11; };

// ---------------------------------------------------------------------------
// K0: w_conv (O,C,3,3) f32 -> Wt2 tiled bf16: [tk(36)][256 o][64 j],
// j = k_local ^ ((o&7)<<3)  (pre-swizzled source; LDS copy stays linear)
// ---------------------------------------------------------------------------
__global__ __launch_bounds__(256) void k0_wt(const float* __restrict__ wconv,
                                             __hip_bfloat16* __restrict__ Wt2) {
  int e = blockIdx.x * 256 + threadIdx.x;      // < 36*16384 = 589824
  int tk = e >> 14;
  int r  = e & 16383;
  int o  = r >> 6, j = r & 63;
  int kl = j ^ ((o & 7) << 3);
  int k  = tk * 64 + kl;
  int kk = k >> 8, c = k & 255;
  float v = wconv[(o * CIN + c) * KK9 + kk];
  Wt2[e] = __float2bfloat16(v);
}

// ---------------------------------------------------------------------------
// K0b: w_off (27,C,3,3) f32 -> Wot tiled bf16: [tk(36)][32 oc][64 j],
// j = k_local ^ ((oc&7)<<3)
// ---------------------------------------------------------------------------
__global__ __launch_bounds__(256) void k0b_wot(const float* __restrict__ woff,
                                               __hip_bfloat16* __restrict__ Wot) {
  int e = blockIdx.x * 256 + threadIdx.x;      // < 36*2048 = 73728
  int tk = e >> 11;
  int r  = e & 2047;
  int ocl = r >> 6, j = r & 63;
  int kl = j ^ ((ocl & 7) << 3);
  int k = tk * 64 + kl;
  int kk = k >> 8, c = k & 255;
  float v = (ocl < 27) ? woff[((size_t)(ocl * 256 + c)) * 9 + kk] : 0.f;
  Wot[e] = __float2bfloat16(v);
}

// ---------------------------------------------------------------------------
// KT: transpose x (B,C,H,W) f32 -> xTh[b][hw][c] bf16 (channel-contiguous)
// ---------------------------------------------------------------------------
__global__ __launch_bounds__(256) void kt_xt(const float* __restrict__ x,
                                             __hip_bfloat16* __restrict__ xTh) {
  __shared__ float t[64][65];
  int blk = blockIdx.x;
  int hwg = blk & 63;
  int cg  = (blk >> 6) & 3;
  int b   = blk >> 8;
  int hw0 = hwg * 64, c0 = cg * 64;
  int l = threadIdx.x & 63, q = threadIdx.x >> 6;
  const float* xb = x + ((size_t)(b * 256 + c0) << 12) + hw0;
#pragma unroll
  for (int i = 0; i < 16; ++i) {
    int cl = q * 16 + i;
    t[cl][l] = xb[((size_t)cl << 12) + l];
  }
  __syncthreads();
  __hip_bfloat16* xTb = xTh + (((size_t)b << 12) + hw0) * 256 + c0;
#pragma unroll
  for (int i = 0; i < 16; ++i) {
    int hwl = q * 16 + i;
    xTb[(size_t)hwl * 256 + l] = __float2bfloat16(t[l][hwl]);
  }
}

// ---------------------------------------------------------------------------
// K1: offset conv as MFMA GEMM. 32 m x 32 oc per block, grid 512 (2/CU).
// ---------------------------------------------------------------------------
__global__ __launch_bounds__(256) void k1_omgemm(const __hip_bfloat16* __restrict__ xTh,
                                                 const __hip_bfloat16* __restrict__ Wot,
                                                 const float* __restrict__ boff,
                                                 float* __restrict__ om) {
  __shared__ __align__(16) __hip_bfloat16 sP[32 * 64];    // 4 KB
  __shared__ __align__(16) __hip_bfloat16 sWo[32 * 64];   // 4 KB
  int bid = blockIdx.x;
  int tm = ((bid & 7) << 6) | (bid >> 3);   // chunked XCD swizzle, 0..511
  int tid = threadIdx.x;
  int wv = tid >> 6, lane = tid & 63;
  int lo = lane & 15, hi = lane >> 4;
  int wr = wv >> 1, wc = wv & 1;

  int row = tid >> 3;           // 0..31
  int kb  = (tid & 7) * 8;      // 0..56
  int colz = kb ^ ((row & 7) << 3);

  int m_s = tm * 32 + row;
  int b_s = m_s >> 12, hw_s = m_s & 4095, h_s = hw_s >> 6, w_s = hw_s & 63;

  f32x4 acc = {0.f, 0.f, 0.f, 0.f};

  for (int tk = 0; tk < NKSTEP; ++tk) {
    async16((const char*)Wot + (size_t)tk * 4096 + tid * 16, (char*)sWo + tid * 16);

    int kk = tk >> 2, cc = tk & 3;
    int ky = kk / 3, kx = kk - ky * 3;
    int yy = h_s + ky - 1, xx = w_s + kx - 1;
    bool valid = ((unsigned)yy < 64u) && ((unsigned)xx < 64u);
    short8 h8 = {0, 0, 0, 0, 0, 0, 0, 0};
    if (valid)
      h8 = *(const short8*)(xTh + ((((size_t)b_s << 12) + yy * 64 + xx) << 8) + cc * 64 + kb);
    *(short8*)&sP[row * 64 + colz] = h8;
    __syncthreads();

#pragma unroll
    for (int kc = 0; kc < 2; ++kc) {
      int cz = (kc * 32 + hi * 8) ^ ((lo & 7) << 3);
      short8 bfr = *(const short8*)&sP[(wr * 16 + lo) * 64 + cz];
      short8 a   = *(const short8*)&sWo[(wc * 16 + lo) * 64 + cz];
      acc = __builtin_amdgcn_mfma_f32_16x16x32_bf16(a, bfr, acc, 0, 0, 0);
    }
    __syncthreads();
  }

  int m_o = tm * 32 + wr * 16 + lo;
  int b_o = m_o >> 12, hw_o = m_o & 4095;
#pragma unroll
  for (int r = 0; r < 4; ++r) {
    int oc = wc * 16 + hi * 4 + r;
    if (oc < 27)
      om[(((size_t)(b_o * 27 + oc)) << 12) + hw_o] = acc[r] + boff[oc];
  }
}

// ---------------------------------------------------------------------------
// K23: fused deformable-gather + GEMM. 64 m x 256 o per block, grid 256,
// 512 thr (8 waves; wave wv owns o in [wv*32, wv*32+32)).
// SINGLE-barrier 2-deep pipeline: double-buffered sW (DMA) + sV (reg-staged
// taps). Per step, one unbarriered region holds {W-DMA(tk+1), V-build(tk+1),
// tap-issue(tk+2), MFMA(tk)} so VALU/MFMA/ds ops interleave; then counted
// vmcnt(4) (drains own W-DMA, keeps taps in flight) + lgkmcnt(0) + s_barrier.
// Invariant: taps(t) are issued BEFORE W-DMA(t) -> the compiler's automatic
// vmcnt wait on taps(t) implies W-DMA(t-1) retired (in-order retirement),
// and the explicit vmcnt(4) before each barrier makes every wave's own
// W-DMA(tk+1) land before any wave reads it next step (race-free).
// ---------------------------------------------------------------------------
__global__ __launch_bounds__(512, 4) void k23_fused(const __hip_bfloat16* __restrict__ xTh,
                                                    const float* __restrict__ om,
                                                    const __hip_bfloat16* __restrict__ Wt2,
                                                    float* __restrict__ out) {
  __shared__ __align__(16) __hip_bfloat16 sW[2][256 * 64];   // 64 KB
  __shared__ __align__(16) __hip_bfloat16 sV[2][64 * 64];    // 16 KB
  __shared__ float sw00[576], sw01[576], sw10[576], sw11[576];   // 9.2 KB
  __shared__ int   so00[576], so01[576], so10[576], so11[576];   // 9.2 KB

  int bid = blockIdx.x;
  int tm = ((bid & 7) << 5) | (bid >> 3);   // chunked XCD swizzle, 0..255
  int tid = threadIdx.x;
  int wv = tid >> 6, lane = tid & 63;
  int lo = lane & 15, hi = lane >> 4;
  int b = tm >> 6;
  int m0 = tm * 64;

  // ---- prologue A: gather params for (kk 0..8) x (row 0..63) ----
  for (int it = tid; it < 576; it += 512) {
    int kk = it >> 6, row = it & 63;
    int m = m0 + row;
    int hw = m & 4095, h = hw >> 6, w = hw & 63;
    const float* omb = om + ((size_t)(b * 27) << 12) + hw;
    float dy = omb[(size_t)(2 * kk) << 12];
    float dx = omb[(size_t)(2 * kk + 1) << 12];
    float mz = omb[(size_t)(18 + kk) << 12];
    int ky = kk / 3, kx = kk - ky * 3;
    float py = dy + (float)(h - 1 + ky);
    float px = dx + (float)(w - 1 + kx);
    float y0f = floorf(py), x0f = floorf(px);
    float wy = py - y0f, wx = px - x0f;
    int y0 = (int)y0f, x0 = (int)x0f;
    bool vy0 = (unsigned)y0 < 64u, vy1 = (unsigned)(y0 + 1) < 64u;
    bool vx0 = (unsigned)x0 < 64u, vx1 = (unsigned)(x0 + 1) < 64u;
    int cy0 = min(max(y0, 0), 63), cy1 = min(max(y0 + 1, 0), 63);
    int cx0 = min(max(x0, 0), 63), cx1 = min(max(x0 + 1, 0), 63);
    float mask = 1.f / (1.f + __expf(-mz));
    sw00[it] = (vy0 && vx0) ? (1.f - wy) * (1.f - wx) * mask : 0.f;
    sw01[it] = (vy0 && vx1) ? (1.f - wy) * wx * mask : 0.f;
    sw10[it] = (vy1 && vx0) ? wy * (1.f - wx) * mask : 0.f;
    sw11[it] = (vy1 && vx1) ? wy * wx * mask : 0.f;
    so00[it] = cy0 * 64 + cx0;
    so01[it] = cy0 * 64 + cx1;
    so10[it] = cy1 * 64 + cx0;
    so11[it] = cy1 * 64 + cx1;
  }
  __syncthreads();   // params visible (one-time full sync)

  const __hip_bfloat16* xb = xTh + ((size_t)b << 20);
  int vrow = tid >> 3;          // 0..63 (8 threads/row, 8 ch each)
  int chq  = tid & 7;
  int colz = (chq * 8) ^ ((vrow & 7) << 3);

  auto loadTaps = [&](int tkq, Taps& T) {
    int it = (tkq >> 2) * 64 + vrow;
    const __hip_bfloat16* base = xb + (tkq & 3) * 64 + chq * 8;
    T.t00 = *(const short8*)(base + (size_t)so00[it] * 256);
    T.t01 = *(const short8*)(base + (size_t)so01[it] * 256);
    T.t10 = *(const short8*)(base + (size_t)so10[it] * 256);
    T.t11 = *(const short8*)(base + (size_t)so11[it] * 256);
  };
  auto buildV = [&](int tkq, const Taps& T, int buf) {
    int it = (tkq >> 2) * 64 + vrow;
    float a00 = sw00[it], a01 = sw01[it], a10 = sw10[it], a11 = sw11[it];
    __hip_bfloat16 h8[8];
#pragma unroll
    for (int j = 0; j < 8; ++j) {
      float v = a00 * b2f(T.t00[j]) + a01 * b2f(T.t01[j])
              + a10 * b2f(T.t10[j]) + a11 * b2f(T.t11[j]);
      h8[j] = __float2bfloat16(v);
    }
    *(short8*)&sV[buf][vrow * 64 + colz] = *(const short8*)h8;
  };
  auto dmaW = [&](int tkq, int buf) {
#pragma unroll
    for (int j = 0; j < 4; ++j) {
      int off = (j * 512 + tid) * 16;
      async16((const char*)Wt2 + (size_t)tkq * 32768 + off, (char*)sW[buf] + off);
    }
  };

  f32x4 zero4 = {0.f, 0.f, 0.f, 0.f};
  f32x4 acc[2][4];
#pragma unroll
  for (int fo = 0; fo < 2; ++fo)
#pragma unroll
    for (int fm = 0; fm < 4; ++fm) acc[fo][fm] = zero4;

  Taps TA, TB;
  // ---- prologue B: W(0) DMA; taps(0)->TA (after DMA: wait(TA) => DMA done);
  //      build V(0)->sV[0]; taps(1)->TB ----
  dmaW(0, 0);
  loadTaps(0, TA);
  buildV(0, TA, 0);
  loadTaps(1, TB);
  asm volatile("s_waitcnt lgkmcnt(0)" ::: "memory");
  __builtin_amdgcn_s_barrier();

  auto body = [&](int tk, Taps& Tuse, Taps& Tload) {
    int cb = tk & 1, nb = cb ^ 1;
    bool more1 = (tk + 1 < NKSTEP), more2 = (tk + 2 < NKSTEP);
    if (more1) {
      dmaW(tk + 1, nb);          // W-DMA first...
      buildV(tk + 1, Tuse, nb);  // (auto vmcnt wait on Tuse => W-DMA(tk) retired)
    }
    if (more2) loadTaps(tk + 2, Tload);  // ...taps after (ordering invariant)

    __builtin_amdgcn_s_setprio(1);
#pragma unroll
    for (int kc = 0; kc < 2; ++kc) {
      int cz = (kc * 32 + hi * 8) ^ ((lo & 7) << 3);
      short8 bv[4], av[2];
#pragma unroll
      for (int fm = 0; fm < 4; ++fm)
        bv[fm] = *(const short8*)&sV[cb][(fm * 16 + lo) * 64 + cz];
#pragma unroll
      for (int fo = 0; fo < 2; ++fo)
        av[fo] = *(const short8*)&sW[cb][(wv * 32 + fo * 16 + lo) * 64 + cz];
#pragma unroll
      for (int fo = 0; fo < 2; ++fo)
#pragma unroll
        for (int fm = 0; fm < 4; ++fm)
          acc[fo][fm] = __builtin_amdgcn_mfma_f32_16x16x32_bf16(av[fo], bv[fm], acc[fo][fm], 0, 0, 0);
    }
    __builtin_amdgcn_s_setprio(0);

    if (more1) {
      if (more2) asm volatile("s_waitcnt vmcnt(4)" ::: "memory");   // drain own W-DMA, keep taps
      else       asm volatile("s_waitcnt vmcnt(0)" ::: "memory");   // tail: drain everything
      asm volatile("s_waitcnt lgkmcnt(0)" ::: "memory");            // V ds_writes visible
      __builtin_amdgcn_s_barrier();
    }
  };

  for (int tkp = 0; tkp < NKSTEP; tkp += 2) {
    body(tkp,     TB, TA);
    body(tkp + 1, TA, TB);
  }

  // epilogue: C layout col = lane&15 -> m, row = hi*4+r -> o
  int hwbase = m0 & 4095;
#pragma unroll
  for (int fo = 0; fo < 2; ++fo) {
    int o = wv * 32 + fo * 16 + hi * 4;
#pragma unroll
    for (int fm = 0; fm < 4; ++fm) {
      int mloc = hwbase + fm * 16 + lo;
#pragma unroll
      for (int r = 0; r < 4; ++r)
        out[((size_t)(b * 256 + o + r)) * 4096 + mloc] = acc[fo][fm][r];
    }
  }
}

// ---------------------------------------------------------------------------
extern "C" void kernel_launch(void* const* d_in, const int* in_sizes, int n_in,
                              void* d_out, int out_size, void* d_ws, size_t ws_size,
                              hipStream_t stream) {
  (void)in_sizes; (void)n_in; (void)out_size; (void)ws_size;
  const float* x     = (const float*)d_in[0];
  const float* woff  = (const float*)d_in[1];
  const float* boff  = (const float*)d_in[2];
  const float* wconv = (const float*)d_in[3];
  char* ws = (char*)d_ws;
  float* om   = (float*)(ws + OM_OFF);
  __hip_bfloat16* xTh = (__hip_bfloat16*)(ws + XT_OFF);
  __hip_bfloat16* Wt2 = (__hip_bfloat16*)(ws + WT_OFF);
  __hip_bfloat16* Wot = (__hip_bfloat16*)(ws + WOT_OFF);
  float* out = (float*)d_out;

  hipLaunchKernelGGL(k0_wt,     dim3(2304), dim3(256), 0, stream, wconv, Wt2);
  hipLaunchKernelGGL(k0b_wot,   dim3(288),  dim3(256), 0, stream, woff, Wot);
  hipLaunchKernelGGL(kt_xt,     dim3(1024), dim3(256), 0, stream, x, xTh);
  hipLaunchKernelGGL(k1_omgemm, dim3(512),  dim3(256), 0, stream, xTh, Wot, boff, om);
  hipLaunchKernelGGL(k23_fused, dim3(256),  dim3(512), 0, stream, xTh, om, Wt2, out);
}

// Round 13
// 79.308 us; speedup vs baseline: 1.0083x; 1.0083x over previous
//
#include <hip/hip_runtime.h>
#include <hip/hip_bf16.h>

// Problem constants
#define XH   64
#define XW   64
#define CIN  256
#define COUT 256
#define BATCH 4
#define KK9  9
#define M_TOT 16384      // BATCH*XH*XW
#define K_TOT 2304       // KK9*CIN
#define NKSTEP 36        // K_TOT/64

typedef __attribute__((ext_vector_type(8))) short short8;
typedef __attribute__((ext_vector_type(4))) short short4v;
typedef __attribute__((ext_vector_type(4))) float f32x4;

// Workspace layout (bytes)
#define OM_OFF   0
#define OM_BYTES (BATCH*27*4096*4)            // 1,769,472
#define XT_OFF   (OM_OFF + OM_BYTES)
#define XT_BYTES (BATCH*4096*CIN*2)           // 8,388,608 (bf16)
#define WT_OFF   (XT_OFF + XT_BYTES)
#define WT_BYTES (COUT*K_TOT*2)               // 1,179,648  Wt3: A-fragment-ordered (see k0)
#define WOT_OFF  (WT_OFF + WT_BYTES)
#define WOT_BYTES (36*32*64*2)                // 147,456    ([tk][32oc][64j], XOR-pre-swizzled)

__device__ __forceinline__ void async16(const void* g, void* l) {
  __builtin_amdgcn_global_load_lds((const __attribute__((address_space(1))) void*)g,
                                   (__attribute__((address_space(3))) void*)l,
                                   16, 0, 0);
}

__device__ __forceinline__ float b2f(short s) {
  union { float f; unsigned u; } x;
  x.u = ((unsigned)(unsigned short)s) << 16;
  return x.f;
}

struct Taps { short8 t00, t01, t10, t11; };

// ---------------------------------------------------------------------------
// K0: w_conv (O,C,3,3) f32 -> Wt3 bf16 in EXACT per-lane A-fragment order:
// Wt3[tk(36)][og(16)][kc(2)][lane(64)][j(8)], value =
//   W[o = og*16 + (lane&15)][k = tk*64 + kc*32 + (lane>>4)*8 + j]
// so a wave's A-fragment = ONE coalesced 1KB load at base + lane*16.
// ---------------------------------------------------------------------------
__global__ __launch_bounds__(256) void k0_wt(const float* __restrict__ wconv,
                                             __hip_bfloat16* __restrict__ Wt3) {
  int e = blockIdx.x * 256 + threadIdx.x;      // < 36*16*2*64*8 = 589824
  int j3   = e & 7;
  int lane = (e >> 3) & 63;
  int kc   = (e >> 9) & 1;
  int og   = (e >> 10) & 15;
  int tk   = e >> 14;
  int o = og * 16 + (lane & 15);
  int k = tk * 64 + kc * 32 + ((lane >> 4) << 3) + j3;
  int kk = k >> 8, c = k & 255;
  float v = wconv[(o * CIN + c) * KK9 + kk];
  Wt3[e] = __float2bfloat16(v);
}

// ---------------------------------------------------------------------------
// K0b: w_off (27,C,3,3) f32 -> Wot tiled bf16: [tk(36)][32 oc][64 j],
// j = k_local ^ ((oc&7)<<3)
// ---------------------------------------------------------------------------
__global__ __launch_bounds__(256) void k0b_wot(const float* __restrict__ woff,
                                               __hip_bfloat16* __restrict__ Wot) {
  int e = blockIdx.x * 256 + threadIdx.x;      // < 36*2048 = 73728
  int tk = e >> 11;
  int r  = e & 2047;
  int ocl = r >> 6, j = r & 63;
  int kl = j ^ ((ocl & 7) << 3);
  int k = tk * 64 + kl;
  int kk = k >> 8, c = k & 255;
  float v = (ocl < 27) ? woff[((size_t)(ocl * 256 + c)) * 9 + kk] : 0.f;
  Wot[e] = __float2bfloat16(v);
}

// ---------------------------------------------------------------------------
// KT: transpose x (B,C,H,W) f32 -> xTh[b][hw][c] bf16 (channel-contiguous)
// ---------------------------------------------------------------------------
__global__ __launch_bounds__(256) void kt_xt(const float* __restrict__ x,
                                             __hip_bfloat16* __restrict__ xTh) {
  __shared__ float t[64][65];
  int blk = blockIdx.x;
  int hwg = blk & 63;
  int cg  = (blk >> 6) & 3;
  int b   = blk >> 8;
  int hw0 = hwg * 64, c0 = cg * 64;
  int l = threadIdx.x & 63, q = threadIdx.x >> 6;
  const float* xb = x + ((size_t)(b * 256 + c0) << 12) + hw0;
#pragma unroll
  for (int i = 0; i < 16; ++i) {
    int cl = q * 16 + i;
    t[cl][l] = xb[((size_t)cl << 12) + l];
  }
  __syncthreads();
  __hip_bfloat16* xTb = xTh + (((size_t)b << 12) + hw0) * 256 + c0;
#pragma unroll
  for (int i = 0; i < 16; ++i) {
    int hwl = q * 16 + i;
    xTb[(size_t)hwl * 256 + l] = __float2bfloat16(t[l][hwl]);
  }
}

// ---------------------------------------------------------------------------
// K1: offset conv as MFMA GEMM. 32 m x 32 oc per block, grid 512 (2/CU).
// ---------------------------------------------------------------------------
__global__ __launch_bounds__(256) void k1_omgemm(const __hip_bfloat16* __restrict__ xTh,
                                                 const __hip_bfloat16* __restrict__ Wot,
                                                 const float* __restrict__ boff,
                                                 float* __restrict__ om) {
  __shared__ __align__(16) __hip_bfloat16 sP[32 * 64];    // 4 KB
  __shared__ __align__(16) __hip_bfloat16 sWo[32 * 64];   // 4 KB
  int bid = blockIdx.x;
  int tm = ((bid & 7) << 6) | (bid >> 3);   // chunked XCD swizzle, 0..511
  int tid = threadIdx.x;
  int wv = tid >> 6, lane = tid & 63;
  int lo = lane & 15, hi = lane >> 4;
  int wr = wv >> 1, wc = wv & 1;

  int row = tid >> 3;           // 0..31
  int kb  = (tid & 7) * 8;      // 0..56
  int colz = kb ^ ((row & 7) << 3);

  int m_s = tm * 32 + row;
  int b_s = m_s >> 12, hw_s = m_s & 4095, h_s = hw_s >> 6, w_s = hw_s & 63;

  f32x4 acc = {0.f, 0.f, 0.f, 0.f};

  for (int tk = 0; tk < NKSTEP; ++tk) {
    async16((const char*)Wot + (size_t)tk * 4096 + tid * 16, (char*)sWo + tid * 16);

    int kk = tk >> 2, cc = tk & 3;
    int ky = kk / 3, kx = kk - ky * 3;
    int yy = h_s + ky - 1, xx = w_s + kx - 1;
    bool valid = ((unsigned)yy < 64u) && ((unsigned)xx < 64u);
    short8 h8 = {0, 0, 0, 0, 0, 0, 0, 0};
    if (valid)
      h8 = *(const short8*)(xTh + ((((size_t)b_s << 12) + yy * 64 + xx) << 8) + cc * 64 + kb);
    *(short8*)&sP[row * 64 + colz] = h8;
    __syncthreads();

#pragma unroll
    for (int kc = 0; kc < 2; ++kc) {
      int cz = (kc * 32 + hi * 8) ^ ((lo & 7) << 3);
      short8 bfr = *(const short8*)&sP[(wr * 16 + lo) * 64 + cz];
      short8 a   = *(const short8*)&sWo[(wc * 16 + lo) * 64 + cz];
      acc = __builtin_amdgcn_mfma_f32_16x16x32_bf16(a, bfr, acc, 0, 0, 0);
    }
    __syncthreads();
  }

  int m_o = tm * 32 + wr * 16 + lo;
  int b_o = m_o >> 12, hw_o = m_o & 4095;
#pragma unroll
  for (int r = 0; r < 4; ++r) {
    int oc = wc * 16 + hi * 4 + r;
    if (oc < 27)
      om[(((size_t)(b_o * 27 + oc)) << 12) + hw_o] = acc[r] + boff[oc];
  }
}

// ---------------------------------------------------------------------------
// K23: fused deformable-gather + GEMM. 64 m x 256 o per block, grid 256,
// 512 thr (8 waves; wave wv owns o in [wv*32, wv*32+32)).
// W NEVER touches LDS: each wave loads its A-fragments straight from the
// fragment-ordered Wt3 (one coalesced 1KB load per fragment, L2-resident),
// double-buffered in registers. LDS carries only sV (double-buffered 16KB).
// One barrier per K-step (lgkmcnt(0) for V ds_writes); all vmcnt waits are
// compiler-automatic on registers whose loads were issued >= 1 step earlier.
// ---------------------------------------------------------------------------
__global__ __launch_bounds__(512, 2) void k23_fused(const __hip_bfloat16* __restrict__ xTh,
                                                    const float* __restrict__ om,
                                                    const __hip_bfloat16* __restrict__ Wt3,
                                                    float* __restrict__ out) {
  __shared__ __align__(16) __hip_bfloat16 sV[2][64 * 64];    // 16 KB
  __shared__ float sw00[576], sw01[576], sw10[576], sw11[576];   // 9.2 KB
  __shared__ int   so00[576], so01[576], so10[576], so11[576];   // 9.2 KB

  int bid = blockIdx.x;
  int tm = ((bid & 7) << 5) | (bid >> 3);   // chunked XCD swizzle, 0..255
  int tid = threadIdx.x;
  int wv = tid >> 6, lane = tid & 63;
  int lo = lane & 15, hi = lane >> 4;
  int b = tm >> 6;
  int m0 = tm * 64;

  // ---- prologue A: gather params for (kk 0..8) x (row 0..63) ----
  for (int it = tid; it < 576; it += 512) {
    int kk = it >> 6, row = it & 63;
    int m = m0 + row;
    int hw = m & 4095, h = hw >> 6, w = hw & 63;
    const float* omb = om + ((size_t)(b * 27) << 12) + hw;
    float dy = omb[(size_t)(2 * kk) << 12];
    float dx = omb[(size_t)(2 * kk + 1) << 12];
    float mz = omb[(size_t)(18 + kk) << 12];
    int ky = kk / 3, kx = kk - ky * 3;
    float py = dy + (float)(h - 1 + ky);
    float px = dx + (float)(w - 1 + kx);
    float y0f = floorf(py), x0f = floorf(px);
    float wy = py - y0f, wx = px - x0f;
    int y0 = (int)y0f, x0 = (int)x0f;
    bool vy0 = (unsigned)y0 < 64u, vy1 = (unsigned)(y0 + 1) < 64u;
    bool vx0 = (unsigned)x0 < 64u, vx1 = (unsigned)(x0 + 1) < 64u;
    int cy0 = min(max(y0, 0), 63), cy1 = min(max(y0 + 1, 0), 63);
    int cx0 = min(max(x0, 0), 63), cx1 = min(max(x0 + 1, 0), 63);
    float mask = 1.f / (1.f + __expf(-mz));
    sw00[it] = (vy0 && vx0) ? (1.f - wy) * (1.f - wx) * mask : 0.f;
    sw01[it] = (vy0 && vx1) ? (1.f - wy) * wx * mask : 0.f;
    sw10[it] = (vy1 && vx0) ? wy * (1.f - wx) * mask : 0.f;
    sw11[it] = (vy1 && vx1) ? wy * wx * mask : 0.f;
    so00[it] = cy0 * 64 + cx0;
    so01[it] = cy0 * 64 + cx1;
    so10[it] = cy1 * 64 + cx0;
    so11[it] = cy1 * 64 + cx1;
  }
  __syncthreads();   // params visible (one-time full sync)

  const __hip_bfloat16* xb = xTh + ((size_t)b << 20);
  int vrow = tid >> 3;          // 0..63 (8 threads/row, 8 ch each)
  int chq  = tid & 7;
  int colz = (chq * 8) ^ ((vrow & 7) << 3);

  auto loadTaps = [&](int tkq, Taps& T) {
    int it = (tkq >> 2) * 64 + vrow;
    const __hip_bfloat16* base = xb + (tkq & 3) * 64 + chq * 8;
    T.t00 = *(const short8*)(base + (size_t)so00[it] * 256);
    T.t01 = *(const short8*)(base + (size_t)so01[it] * 256);
    T.t10 = *(const short8*)(base + (size_t)so10[it] * 256);
    T.t11 = *(const short8*)(base + (size_t)so11[it] * 256);
  };
  auto buildV = [&](int tkq, const Taps& T, int buf) {
    int it = (tkq >> 2) * 64 + vrow;
    float a00 = sw00[it], a01 = sw01[it], a10 = sw10[it], a11 = sw11[it];
    __hip_bfloat16 h8[8];
#pragma unroll
    for (int j = 0; j < 8; ++j) {
      float v = a00 * b2f(T.t00[j]) + a01 * b2f(T.t01[j])
              + a10 * b2f(T.t10[j]) + a11 * b2f(T.t11[j]);
      h8[j] = __float2bfloat16(v);
    }
    *(short8*)&sV[buf][vrow * 64 + colz] = *(const short8*)h8;
  };
  // A-fragment loads: fragment (tk, fo, kc) lives at
  //   Wt3 + ((tk*16 + (wv*2+fo))*2 + kc)*1024 bytes + lane*16
  auto loadW = [&](int tkq, short8 (&aw)[4]) {
#pragma unroll
    for (int fo = 0; fo < 2; ++fo)
#pragma unroll
      for (int kc = 0; kc < 2; ++kc)
        aw[fo * 2 + kc] = *(const short8*)((const char*)Wt3
                          + ((((size_t)tkq * 16 + (wv * 2 + fo)) * 2 + kc) << 10)
                          + lane * 16);
  };

  f32x4 zero4 = {0.f, 0.f, 0.f, 0.f};
  f32x4 acc[2][4];
#pragma unroll
  for (int fo = 0; fo < 2; ++fo)
#pragma unroll
    for (int fm = 0; fm < 4; ++fm) acc[fo][fm] = zero4;

  Taps TA, TB;
  short8 awA[4], awB[4];
  // ---- prologue B: av(0)->awA; taps(0)->TA; V(0)->sV[0]; taps(1)->TB ----
  loadW(0, awA);
  loadTaps(0, TA);
  buildV(0, TA, 0);
  loadTaps(1, TB);
  asm volatile("s_waitcnt lgkmcnt(0)" ::: "memory");
  __builtin_amdgcn_s_barrier();

  auto body = [&](int tk, Taps& Tuse, Taps& Tload,
                  short8 (&awUse)[4], short8 (&awLoad)[4]) {
    int cb = tk & 1, nb = cb ^ 1;
    bool more1 = (tk + 1 < NKSTEP), more2 = (tk + 2 < NKSTEP);
    if (more1) loadW(tk + 1, awLoad);        // issue early, waits at use next step
    if (more2) loadTaps(tk + 2, Tload);
    if (more1) buildV(tk + 1, Tuse, nb);     // auto-wait on Tuse (1 step old)

    __builtin_amdgcn_s_setprio(1);
#pragma unroll
    for (int kc = 0; kc < 2; ++kc) {
      int cz = (kc * 32 + hi * 8) ^ ((lo & 7) << 3);
      short8 bv[4];
#pragma unroll
      for (int fm = 0; fm < 4; ++fm)
        bv[fm] = *(const short8*)&sV[cb][(fm * 16 + lo) * 64 + cz];
#pragma unroll
      for (int fo = 0; fo < 2; ++fo)
#pragma unroll
        for (int fm = 0; fm < 4; ++fm)
          acc[fo][fm] = __builtin_amdgcn_mfma_f32_16x16x32_bf16(awUse[fo * 2 + kc], bv[fm], acc[fo][fm], 0, 0, 0);
    }
    __builtin_amdgcn_s_setprio(0);

    if (more1) {
      asm volatile("s_waitcnt lgkmcnt(0)" ::: "memory");   // V(tk+1) ds_writes done
      __builtin_amdgcn_s_barrier();
    }
  };

  for (int tkp = 0; tkp < NKSTEP; tkp += 2) {
    body(tkp,     TB, TA, awA, awB);
    body(tkp + 1, TA, TB, awB, awA);
  }

  // epilogue: C layout col = lane&15 -> m, row = hi*4+r -> o
  int hwbase = m0 & 4095;
#pragma unroll
  for (int fo = 0; fo < 2; ++fo) {
    int o = wv * 32 + fo * 16 + hi * 4;
#pragma unroll
    for (int fm = 0; fm < 4; ++fm) {
      int mloc = hwbase + fm * 16 + lo;
#pragma unroll
      for (int r = 0; r < 4; ++r)
        out[((size_t)(b * 256 + o + r)) * 4096 + mloc] = acc[fo][fm][r];
    }
  }
}

// ---------------------------------------------------------------------------
extern "C" void kernel_launch(void* const* d_in, const int* in_sizes, int n_in,
                              void* d_out, int out_size, void* d_ws, size_t ws_size,
                              hipStream_t stream) {
  (void)in_sizes; (void)n_in; (void)out_size; (void)ws_size;
  const float* x     = (const float*)d_in[0];
  const float* woff  = (const float*)d_in[1];
  const float* boff  = (const float*)d_in[2];
  const float* wconv = (const float*)d_in[3];
  char* ws = (char*)d_ws;
  float* om   = (float*)(ws + OM_OFF);
  __hip_bfloat16* xTh = (__hip_bfloat16*)(ws + XT_OFF);
  __hip_bfloat16* Wt3 = (__hip_bfloat16*)(ws + WT_OFF);
  __hip_bfloat16* Wot = (__hip_bfloat16*)(ws + WOT_OFF);
  float* out = (float*)d_out;

  hipLaunchKernelGGL(k0_wt,     dim3(2304), dim3(256), 0, stream, wconv, Wt3);
  hipLaunchKernelGGL(k0b_wot,   dim3(288),  dim3(256), 0, stream, woff, Wot);
  hipLaunchKernelGGL(kt_xt,     dim3(1024), dim3(256), 0, stream, x, xTh);
  hipLaunchKernelGGL(k1_omgemm, dim3(512),  dim3(256), 0, stream, xTh, Wot, boff, om);
  hipLaunchKernelGGL(k23_fused, dim3(256),  dim3(512), 0, stream, xTh, om, Wt3, out);
}

// Round 14
// 74.938 us; speedup vs baseline: 1.0671x; 1.0583x over previous
//
#include <hip/hip_runtime.h>
#include <hip/hip_bf16.h>

// Problem constants
#define XH   64
#define XW   64
#define CIN  256
#define COUT 256
#define BATCH 4
#define KK9  9
#define M_TOT 16384      // BATCH*XH*XW
#define K_TOT 2304       // KK9*CIN
#define NKSTEP 36        // K_TOT/64

typedef __attribute__((ext_vector_type(8))) short short8;
typedef __attribute__((ext_vector_type(4))) short short4v;
typedef __attribute__((ext_vector_type(4))) float f32x4;

// Workspace layout (bytes)
#define OM_OFF   0
#define OM_BYTES (BATCH*27*4096*4)            // 1,769,472
#define XT_OFF   (OM_OFF + OM_BYTES)
#define XT_BYTES (BATCH*4096*CIN*2)           // 8,388,608 (bf16)
#define WT_OFF   (XT_OFF + XT_BYTES)
#define WT_BYTES (COUT*K_TOT*2)               // 1,179,648  Wt3: A-fragment-ordered (see k0)
#define WOT_OFF  (WT_OFF + WT_BYTES)
#define WOT_BYTES (36*32*64*2)                // 147,456    ([tk][32oc][64j], XOR-pre-swizzled)

__device__ __forceinline__ void async16(const void* g, void* l) {
  __builtin_amdgcn_global_load_lds((const __attribute__((address_space(1))) void*)g,
                                   (__attribute__((address_space(3))) void*)l,
                                   16, 0, 0);
}

__device__ __forceinline__ float b2f(short s) {
  union { float f; unsigned u; } x;
  x.u = ((unsigned)(unsigned short)s) << 16;
  return x.f;
}

struct Taps { short8 t00, t01, t10, t11; };

// ---------------------------------------------------------------------------
// K0: w_conv (O,C,3,3) f32 -> Wt3 bf16 in EXACT per-lane A-fragment order:
// Wt3[tk(36)][og(16)][kc(2)][lane(64)][j(8)], value =
//   W[o = og*16 + (lane&15)][k = tk*64 + kc*32 + (lane>>4)*8 + j]
// ---------------------------------------------------------------------------
__global__ __launch_bounds__(256) void k0_wt(const float* __restrict__ wconv,
                                             __hip_bfloat16* __restrict__ Wt3) {
  int e = blockIdx.x * 256 + threadIdx.x;      // < 589824
  int j3   = e & 7;
  int lane = (e >> 3) & 63;
  int kc   = (e >> 9) & 1;
  int og   = (e >> 10) & 15;
  int tk   = e >> 14;
  int o = og * 16 + (lane & 15);
  int k = tk * 64 + kc * 32 + ((lane >> 4) << 3) + j3;
  int kk = k >> 8, c = k & 255;
  float v = wconv[(o * CIN + c) * KK9 + kk];
  Wt3[e] = __float2bfloat16(v);
}

// ---------------------------------------------------------------------------
// K0b: w_off (27,C,3,3) f32 -> Wot tiled bf16: [tk(36)][32 oc][64 j],
// j = k_local ^ ((oc&7)<<3)
// ---------------------------------------------------------------------------
__global__ __launch_bounds__(256) void k0b_wot(const float* __restrict__ woff,
                                               __hip_bfloat16* __restrict__ Wot) {
  int e = blockIdx.x * 256 + threadIdx.x;      // < 73728
  int tk = e >> 11;
  int r  = e & 2047;
  int ocl = r >> 6, j = r & 63;
  int kl = j ^ ((ocl & 7) << 3);
  int k = tk * 64 + kl;
  int kk = k >> 8, c = k & 255;
  float v = (ocl < 27) ? woff[((size_t)(ocl * 256 + c)) * 9 + kk] : 0.f;
  Wot[e] = __float2bfloat16(v);
}

// ---------------------------------------------------------------------------
// KT: transpose x (B,C,H,W) f32 -> xTh[b][hw][c] bf16
// ---------------------------------------------------------------------------
__global__ __launch_bounds__(256) void kt_xt(const float* __restrict__ x,
                                             __hip_bfloat16* __restrict__ xTh) {
  __shared__ float t[64][65];
  int blk = blockIdx.x;
  int hwg = blk & 63;
  int cg  = (blk >> 6) & 3;
  int b   = blk >> 8;
  int hw0 = hwg * 64, c0 = cg * 64;
  int l = threadIdx.x & 63, q = threadIdx.x >> 6;
  const float* xb = x + ((size_t)(b * 256 + c0) << 12) + hw0;
#pragma unroll
  for (int i = 0; i < 16; ++i) {
    int cl = q * 16 + i;
    t[cl][l] = xb[((size_t)cl << 12) + l];
  }
  __syncthreads();
  __hip_bfloat16* xTb = xTh + (((size_t)b << 12) + hw0) * 256 + c0;
#pragma unroll
  for (int i = 0; i < 16; ++i) {
    int hwl = q * 16 + i;
    xTb[(size_t)hwl * 256 + l] = __float2bfloat16(t[l][hwl]);
  }
}

// ---------------------------------------------------------------------------
// K1: offset conv as MFMA GEMM. 32 m x 32 oc per block, grid 512 (2/CU).
// ---------------------------------------------------------------------------
__global__ __launch_bounds__(256) void k1_omgemm(const __hip_bfloat16* __restrict__ xTh,
                                                 const __hip_bfloat16* __restrict__ Wot,
                                                 const float* __restrict__ boff,
                                                 float* __restrict__ om) {
  __shared__ __align__(16) __hip_bfloat16 sP[32 * 64];    // 4 KB
  __shared__ __align__(16) __hip_bfloat16 sWo[32 * 64];   // 4 KB
  int bid = blockIdx.x;
  int tm = ((bid & 7) << 6) | (bid >> 3);   // chunked XCD swizzle, 0..511
  int tid = threadIdx.x;
  int wv = tid >> 6, lane = tid & 63;
  int lo = lane & 15, hi = lane >> 4;
  int wr = wv >> 1, wc = wv & 1;

  int row = tid >> 3;           // 0..31
  int kb  = (tid & 7) * 8;      // 0..56
  int colz = kb ^ ((row & 7) << 3);

  int m_s = tm * 32 + row;
  int b_s = m_s >> 12, hw_s = m_s & 4095, h_s = hw_s >> 6, w_s = hw_s & 63;

  f32x4 acc = {0.f, 0.f, 0.f, 0.f};

  for (int tk = 0; tk < NKSTEP; ++tk) {
    async16((const char*)Wot + (size_t)tk * 4096 + tid * 16, (char*)sWo + tid * 16);

    int kk = tk >> 2, cc = tk & 3;
    int ky = kk / 3, kx = kk - ky * 3;
    int yy = h_s + ky - 1, xx = w_s + kx - 1;
    bool valid = ((unsigned)yy < 64u) && ((unsigned)xx < 64u);
    short8 h8 = {0, 0, 0, 0, 0, 0, 0, 0};
    if (valid)
      h8 = *(const short8*)(xTh + ((((size_t)b_s << 12) + yy * 64 + xx) << 8) + cc * 64 + kb);
    *(short8*)&sP[row * 64 + colz] = h8;
    __syncthreads();

#pragma unroll
    for (int kc = 0; kc < 2; ++kc) {
      int cz = (kc * 32 + hi * 8) ^ ((lo & 7) << 3);
      short8 bfr = *(const short8*)&sP[(wr * 16 + lo) * 64 + cz];
      short8 a   = *(const short8*)&sWo[(wc * 16 + lo) * 64 + cz];
      acc = __builtin_amdgcn_mfma_f32_16x16x32_bf16(a, bfr, acc, 0, 0, 0);
    }
    __syncthreads();
  }

  int m_o = tm * 32 + wr * 16 + lo;
  int b_o = m_o >> 12, hw_o = m_o & 4095;
#pragma unroll
  for (int r = 0; r < 4; ++r) {
    int oc = wc * 16 + hi * 4 + r;
    if (oc < 27)
      om[(((size_t)(b_o * 27 + oc)) << 12) + hw_o] = acc[r] + boff[oc];
  }
}

// ---------------------------------------------------------------------------
// K23: fused deformable-gather + GEMM. 32 m x 256 o per block, grid 512
// (2 independent blocks/CU -> cross-block phase overlap: one block's MFMA
// phase overlaps the other's V-build, breaking the single-domain lockstep
// that pinned R11-R13 at ~46us). 256 thr (4 waves; wave owns 64 o).
// W: register fragments straight from fragment-ordered Wt3 (L2), dbuf'd.
// V: reg-staged bf16 taps -> VALU bilinear -> double-buffered sV (4KB each).
// One barrier per K-step; vmcnt waits are compiler-automatic on registers
// whose loads were issued a full step earlier.
// ---------------------------------------------------------------------------
__global__ __launch_bounds__(256, 2) void k23_fused(const __hip_bfloat16* __restrict__ xTh,
                                                    const float* __restrict__ om,
                                                    const __hip_bfloat16* __restrict__ Wt3,
                                                    float* __restrict__ out) {
  __shared__ __align__(16) __hip_bfloat16 sV[2][32 * 64];    // 8 KB
  __shared__ float sw00[288], sw01[288], sw10[288], sw11[288];   // 4.6 KB
  __shared__ int   so00[288], so01[288], so10[288], so11[288];   // 4.6 KB

  int bid = blockIdx.x;
  int tm = ((bid & 7) << 6) | (bid >> 3);   // chunked XCD swizzle, 0..511
  int tid = threadIdx.x;
  int wv = tid >> 6, lane = tid & 63;
  int lo = lane & 15, hi = lane >> 4;
  int b = tm >> 7;
  int m0 = tm * 32;

  // ---- prologue A: gather params for (kk 0..8) x (row 0..31) ----
  for (int it = tid; it < 288; it += 256) {
    int kk = it >> 5, row = it & 31;
    int m = m0 + row;
    int hw = m & 4095, h = hw >> 6, w = hw & 63;
    const float* omb = om + ((size_t)(b * 27) << 12) + hw;
    float dy = omb[(size_t)(2 * kk) << 12];
    float dx = omb[(size_t)(2 * kk + 1) << 12];
    float mz = omb[(size_t)(18 + kk) << 12];
    int ky = kk / 3, kx = kk - ky * 3;
    float py = dy + (float)(h - 1 + ky);
    float px = dx + (float)(w - 1 + kx);
    float y0f = floorf(py), x0f = floorf(px);
    float wy = py - y0f, wx = px - x0f;
    int y0 = (int)y0f, x0 = (int)x0f;
    bool vy0 = (unsigned)y0 < 64u, vy1 = (unsigned)(y0 + 1) < 64u;
    bool vx0 = (unsigned)x0 < 64u, vx1 = (unsigned)(x0 + 1) < 64u;
    int cy0 = min(max(y0, 0), 63), cy1 = min(max(y0 + 1, 0), 63);
    int cx0 = min(max(x0, 0), 63), cx1 = min(max(x0 + 1, 0), 63);
    float mask = 1.f / (1.f + __expf(-mz));
    sw00[it] = (vy0 && vx0) ? (1.f - wy) * (1.f - wx) * mask : 0.f;
    sw01[it] = (vy0 && vx1) ? (1.f - wy) * wx * mask : 0.f;
    sw10[it] = (vy1 && vx0) ? wy * (1.f - wx) * mask : 0.f;
    sw11[it] = (vy1 && vx1) ? wy * wx * mask : 0.f;
    so00[it] = cy0 * 64 + cx0;
    so01[it] = cy0 * 64 + cx1;
    so10[it] = cy1 * 64 + cx0;
    so11[it] = cy1 * 64 + cx1;
  }
  __syncthreads();   // params visible (one-time full sync)

  const __hip_bfloat16* xb = xTh + ((size_t)b << 20);
  int vrow = tid >> 3;          // 0..31 (8 threads/row, 8 ch each)
  int chq  = tid & 7;
  int colz = (chq * 8) ^ ((vrow & 7) << 3);

  auto loadTaps = [&](int tkq, Taps& T) {
    int it = (tkq >> 2) * 32 + vrow;
    const __hip_bfloat16* base = xb + (tkq & 3) * 64 + chq * 8;
    T.t00 = *(const short8*)(base + (size_t)so00[it] * 256);
    T.t01 = *(const short8*)(base + (size_t)so01[it] * 256);
    T.t10 = *(const short8*)(base + (size_t)so10[it] * 256);
    T.t11 = *(const short8*)(base + (size_t)so11[it] * 256);
  };
  auto buildV = [&](int tkq, const Taps& T, int buf) {
    int it = (tkq >> 2) * 32 + vrow;
    float a00 = sw00[it], a01 = sw01[it], a10 = sw10[it], a11 = sw11[it];
    __hip_bfloat16 h8[8];
#pragma unroll
    for (int j = 0; j < 8; ++j) {
      float v = a00 * b2f(T.t00[j]) + a01 * b2f(T.t01[j])
              + a10 * b2f(T.t10[j]) + a11 * b2f(T.t11[j]);
      h8[j] = __float2bfloat16(v);
    }
    *(short8*)&sV[buf][vrow * 64 + colz] = *(const short8*)h8;
  };
  // A-fragments: wave wv owns o in [wv*64, wv*64+64) -> og = wv*4+fo.
  // frag (tk, og, kc) at Wt3 + ((tk*16 + og)*2 + kc)*1024 B + lane*16.
  auto loadW = [&](int tkq, short8 (&aw)[8]) {
#pragma unroll
    for (int fo = 0; fo < 4; ++fo)
#pragma unroll
      for (int kc = 0; kc < 2; ++kc)
        aw[fo * 2 + kc] = *(const short8*)((const char*)Wt3
                          + ((((size_t)tkq * 16 + (wv * 4 + fo)) * 2 + kc) << 10)
                          + lane * 16);
  };

  f32x4 zero4 = {0.f, 0.f, 0.f, 0.f};
  f32x4 acc[4][2];
#pragma unroll
  for (int fo = 0; fo < 4; ++fo)
#pragma unroll
    for (int fm = 0; fm < 2; ++fm) acc[fo][fm] = zero4;

  Taps TA, TB;
  short8 awA[8], awB[8];
  // ---- prologue B ----
  loadW(0, awA);
  loadTaps(0, TA);
  buildV(0, TA, 0);
  loadTaps(1, TB);
  asm volatile("s_waitcnt lgkmcnt(0)" ::: "memory");
  __builtin_amdgcn_s_barrier();

  auto body = [&](int tk, Taps& Tuse, Taps& Tload,
                  short8 (&awUse)[8], short8 (&awLoad)[8]) {
    int cb = tk & 1, nb = cb ^ 1;
    bool more1 = (tk + 1 < NKSTEP), more2 = (tk + 2 < NKSTEP);
    if (more1) loadW(tk + 1, awLoad);        // issued early, waits at use next step
    if (more2) loadTaps(tk + 2, Tload);
    if (more1) buildV(tk + 1, Tuse, nb);     // auto-wait on Tuse (1 step old)

    __builtin_amdgcn_s_setprio(1);
#pragma unroll
    for (int kc = 0; kc < 2; ++kc) {
      int cz = (kc * 32 + hi * 8) ^ ((lo & 7) << 3);
      short8 bv[2];
#pragma unroll
      for (int fm = 0; fm < 2; ++fm)
        bv[fm] = *(const short8*)&sV[cb][(fm * 16 + lo) * 64 + cz];
#pragma unroll
      for (int fo = 0; fo < 4; ++fo)
#pragma unroll
        for (int fm = 0; fm < 2; ++fm)
          acc[fo][fm] = __builtin_amdgcn_mfma_f32_16x16x32_bf16(awUse[fo * 2 + kc], bv[fm], acc[fo][fm], 0, 0, 0);
    }
    __builtin_amdgcn_s_setprio(0);

    if (more1) {
      asm volatile("s_waitcnt lgkmcnt(0)" ::: "memory");   // V(tk+1) ds_writes done
      __builtin_amdgcn_s_barrier();
    }
  };

  for (int tkp = 0; tkp < NKSTEP; tkp += 2) {
    body(tkp,     TB, TA, awA, awB);
    body(tkp + 1, TA, TB, awB, awA);
  }

  // epilogue: C layout col = lane&15 -> m, row = hi*4+r -> o
  int hwbase = m0 & 4095;
#pragma unroll
  for (int fo = 0; fo < 4; ++fo) {
    int o = wv * 64 + fo * 16 + hi * 4;
#pragma unroll
    for (int fm = 0; fm < 2; ++fm) {
      int mloc = hwbase + fm * 16 + lo;
#pragma unroll
      for (int r = 0; r < 4; ++r)
        out[((size_t)(b * 256 + o + r)) * 4096 + mloc] = acc[fo][fm][r];
    }
  }
}

// ---------------------------------------------------------------------------
extern "C" void kernel_launch(void* const* d_in, const int* in_sizes, int n_in,
                              void* d_out, int out_size, void* d_ws, size_t ws_size,
                              hipStream_t stream) {
  (void)in_sizes; (void)n_in; (void)out_size; (void)ws_size;
  const float* x     = (const float*)d_in[0];
  const float* woff  = (const float*)d_in[1];
  const float* boff  = (const float*)d_in[2];
  const float* wconv = (const float*)d_in[3];
  char* ws = (char*)d_ws;
  float* om   = (float*)(ws + OM_OFF);
  __hip_bfloat16* xTh = (__hip_bfloat16*)(ws + XT_OFF);
  __hip_bfloat16* Wt3 = (__hip_bfloat16*)(ws + WT_OFF);
  __hip_bfloat16* Wot = (__hip_bfloat16*)(ws + WOT_OFF);
  float* out = (float*)d_out;

  hipLaunchKernelGGL(k0_wt,     dim3(2304), dim3(256), 0, stream, wconv, Wt3);
  hipLaunchKernelGGL(k0b_wot,   dim3(288),  dim3(256), 0, stream, woff, Wot);
  hipLaunchKernelGGL(kt_xt,     dim3(1024), dim3(256), 0, stream, x, xTh);
  hipLaunchKernelGGL(k1_omgemm, dim3(512),  dim3(256), 0, stream, xTh, Wot, boff, om);
  hipLaunchKernelGGL(k23_fused, dim3(512),  dim3(256), 0, stream, xTh, om, Wt3, out);
}

// Round 15
// 69.202 us; speedup vs baseline: 1.1556x; 1.0829x over previous
//
#include <hip/hip_runtime.h>
#include <hip/hip_bf16.h>

// Problem constants
#define XH   64
#define XW   64
#define CIN  256
#define COUT 256
#define BATCH 4
#define KK9  9
#define M_TOT 16384      // BATCH*XH*XW
#define K_TOT 2304       // KK9*CIN
#define NKSTEP 36        // K_TOT/64

typedef __attribute__((ext_vector_type(8))) short short8;
typedef __attribute__((ext_vector_type(4))) float f32x4;

// Workspace layout (bytes)
#define XT_OFF   0
#define XT_BYTES (BATCH*4096*CIN*2)           // 8,388,608 (bf16)
#define WT_OFF   (XT_OFF + XT_BYTES)
#define WT_BYTES (COUT*K_TOT*2)               // 1,179,648  Wt3: A-fragment-ordered (k0)
#define WOT_OFF  (WT_OFF + WT_BYTES)
#define WOT_BYTES (36*2*2*64*8*2)             // 147,456    Wot3: A-fragment-ordered (k0b)

__device__ __forceinline__ float b2f(short s) {
  union { float f; unsigned u; } x;
  x.u = ((unsigned)(unsigned short)s) << 16;
  return x.f;
}

struct Taps { short8 t00, t01, t10, t11; };

// ---------------------------------------------------------------------------
// K0: w_conv (O,C,3,3) f32 -> Wt3 bf16 in EXACT per-lane A-fragment order:
// Wt3[tk(36)][og(16)][kc(2)][lane(64)][j(8)], value =
//   W[o = og*16 + (lane&15)][k = tk*64 + kc*32 + (lane>>4)*8 + j]
// ---------------------------------------------------------------------------
__global__ __launch_bounds__(256) void k0_wt(const float* __restrict__ wconv,
                                             __hip_bfloat16* __restrict__ Wt3) {
  int e = blockIdx.x * 256 + threadIdx.x;      // < 589824
  int j3   = e & 7;
  int lane = (e >> 3) & 63;
  int kc   = (e >> 9) & 1;
  int og   = (e >> 10) & 15;
  int tk   = e >> 14;
  int o = og * 16 + (lane & 15);
  int k = tk * 64 + kc * 32 + ((lane >> 4) << 3) + j3;
  int kk = k >> 8, c = k & 255;
  float v = wconv[(o * CIN + c) * KK9 + kk];
  Wt3[e] = __float2bfloat16(v);
}

// ---------------------------------------------------------------------------
// K0b: w_off (27,C,3,3) f32 -> Wot3 bf16, A-fragment order:
// Wot3[tk(36)][wc(2)][kc(2)][lane(64)][j(8)], value =
//   Woff[oc = wc*16 + (lane&15)][k = tk*64 + kc*32 + (lane>>4)*8 + j]
//   (oc >= 27 zero-padded)
// ---------------------------------------------------------------------------
__global__ __launch_bounds__(256) void k0b_wot(const float* __restrict__ woff,
                                               __hip_bfloat16* __restrict__ Wot3) {
  int e = blockIdx.x * 256 + threadIdx.x;      // < 73728
  int j3   = e & 7;
  int lane = (e >> 3) & 63;
  int kc   = (e >> 9) & 1;
  int wc   = (e >> 10) & 1;
  int tk   = e >> 11;
  int oc = wc * 16 + (lane & 15);
  int k = tk * 64 + kc * 32 + ((lane >> 4) << 3) + j3;
  int kk = k >> 8, c = k & 255;
  float v = (oc < 27) ? woff[((size_t)(oc * 256 + c)) * 9 + kk] : 0.f;
  Wot3[e] = __float2bfloat16(v);
}

// ---------------------------------------------------------------------------
// KT: transpose x (B,C,H,W) f32 -> xTh[b][hw][c] bf16
// ---------------------------------------------------------------------------
__global__ __launch_bounds__(256) void kt_xt(const float* __restrict__ x,
                                             __hip_bfloat16* __restrict__ xTh) {
  __shared__ float t[64][65];
  int blk = blockIdx.x;
  int hwg = blk & 63;
  int cg  = (blk >> 6) & 3;
  int b   = blk >> 8;
  int hw0 = hwg * 64, c0 = cg * 64;
  int l = threadIdx.x & 63, q = threadIdx.x >> 6;
  const float* xb = x + ((size_t)(b * 256 + c0) << 12) + hw0;
#pragma unroll
  for (int i = 0; i < 16; ++i) {
    int cl = q * 16 + i;
    t[cl][l] = xb[((size_t)cl << 12) + l];
  }
  __syncthreads();
  __hip_bfloat16* xTb = xTh + (((size_t)b << 12) + hw0) * 256 + c0;
#pragma unroll
  for (int i = 0; i < 16; ++i) {
    int hwl = q * 16 + i;
    xTb[(size_t)hwl * 256 + l] = __float2bfloat16(t[l][hwl]);
  }
}

// ---------------------------------------------------------------------------
// K23: FULLY fused: phase-1 offset-conv GEMM (own 32 rows -> sOM in LDS),
// phase-2 deformable-gather + main GEMM. 32 m x 256 o per block, grid 512
// (2 blocks/CU), 256 thr (4 waves).
// Phase-1: wave (wr,wc) owns 16m x 16oc quadrant; patch reg-staged 1 step
//   ahead; Wot A-frags direct from fragment-ordered Wot3 (L2); 1 barrier/step.
// Phase-2: identical to R14 main loop (W-frags direct from Wt3; V via
//   reg-staged taps -> dbuf sPV; 1 barrier/step).
// sPV LDS shared between phases (same shape; phases strictly sequential).
// ---------------------------------------------------------------------------
__global__ __launch_bounds__(256, 2) void k23_fused(const __hip_bfloat16* __restrict__ xTh,
                                                    const __hip_bfloat16* __restrict__ Wt3,
                                                    const __hip_bfloat16* __restrict__ Wot3,
                                                    const float* __restrict__ boff,
                                                    float* __restrict__ out) {
  __shared__ __align__(16) __hip_bfloat16 sPV[2][32 * 64];   // 8 KB (phase1: patch; phase2: V)
  __shared__ float sOM[32][32];                               // 4 KB
  __shared__ float sw00[288], sw01[288], sw10[288], sw11[288];   // 4.6 KB
  __shared__ int   so00[288], so01[288], so10[288], so11[288];   // 4.6 KB

  int bid = blockIdx.x;
  int tm = ((bid & 7) << 6) | (bid >> 3);   // chunked XCD swizzle, 0..511
  int tid = threadIdx.x;
  int wv = tid >> 6, lane = tid & 63;
  int lo = lane & 15, hi = lane >> 4;
  int b = tm >> 7;
  int m0 = tm * 32;

  // ===================== PHASE 1: om for own 32 rows =====================
  {
    int wr = wv >> 1, wc = wv & 1;
    int prow = tid >> 3;            // 0..31
    int pkb  = (tid & 7) * 8;       // 0..56
    int pcolz = pkb ^ ((prow & 7) << 3);
    int m_s = m0 + prow;
    int hw_s = m_s & 4095, h_s = hw_s >> 6, w_s = hw_s & 63;

    auto loadPatch = [&](int tkq) -> short8 {
      int kk = tkq >> 2, cc = tkq & 3;
      int ky = kk / 3, kx = kk - ky * 3;
      int yy = h_s + ky - 1, xx = w_s + kx - 1;
      short8 h8 = {0, 0, 0, 0, 0, 0, 0, 0};
      if (((unsigned)yy < 64u) && ((unsigned)xx < 64u))
        h8 = *(const short8*)(xTh + ((((size_t)b << 12) + yy * 64 + xx) << 8) + cc * 64 + pkb);
      return h8;
    };
    auto loadWot = [&](int tkq, short8 (&w2)[2]) {
#pragma unroll
      for (int kc = 0; kc < 2; ++kc)
        w2[kc] = *(const short8*)((const char*)Wot3
                  + ((((size_t)tkq * 2 + wc) * 2 + kc) << 10) + lane * 16);
    };

    f32x4 acc1 = {0.f, 0.f, 0.f, 0.f};
    short8 PA, PB, wUA[2], wUB[2];
    PA = loadPatch(0);
    loadWot(0, wUA);
    *(short8*)&sPV[0][prow * 64 + pcolz] = PA;
    PB = loadPatch(1);
    asm volatile("s_waitcnt lgkmcnt(0)" ::: "memory");
    __builtin_amdgcn_s_barrier();

    auto p1body = [&](int tk, short8& Puse, short8& Pload,
                      short8 (&wU)[2], short8 (&wL)[2]) {
      int cb = tk & 1, nb = cb ^ 1;
      bool more1 = (tk + 1 < NKSTEP), more2 = (tk + 2 < NKSTEP);
      if (more1) {
        loadWot(tk + 1, wL);
        *(short8*)&sPV[nb][prow * 64 + pcolz] = Puse;   // patch(tk+1)
      }
      if (more2) Pload = loadPatch(tk + 2);
#pragma unroll
      for (int kc = 0; kc < 2; ++kc) {
        int cz = (kc * 32 + hi * 8) ^ ((lo & 7) << 3);
        short8 bfr = *(const short8*)&sPV[cb][(wr * 16 + lo) * 64 + cz];
        acc1 = __builtin_amdgcn_mfma_f32_16x16x32_bf16(wU[kc], bfr, acc1, 0, 0, 0);
      }
      if (more1) {
        asm volatile("s_waitcnt lgkmcnt(0)" ::: "memory");
        __builtin_amdgcn_s_barrier();
      }
    };
    for (int tkp = 0; tkp < NKSTEP; tkp += 2) {
      p1body(tkp,     PB, PA, wUA, wUB);
      p1body(tkp + 1, PA, PB, wUB, wUA);
    }

    // epilogue: acc1 -> sOM[row][oc] (+bias). C layout: col=lo -> m, row=hi*4+r -> oc
    int oc0 = wc * 16 + hi * 4;
#pragma unroll
    for (int r = 0; r < 4; ++r) {
      float bias = (oc0 + r < 27) ? boff[oc0 + r] : 0.f;
      sOM[wr * 16 + lo][oc0 + r] = acc1[r] + bias;
    }
  }
  __syncthreads();   // sOM complete

  // ============== PHASE 2 prologue A: gather params from sOM ==============
  for (int it = tid; it < 288; it += 256) {
    int kk = it >> 5, row = it & 31;
    int m = m0 + row;
    int hw = m & 4095, h = hw >> 6, w = hw & 63;
    float dy = sOM[row][2 * kk];
    float dx = sOM[row][2 * kk + 1];
    float mz = sOM[row][18 + kk];
    int ky = kk / 3, kx = kk - ky * 3;
    float py = dy + (float)(h - 1 + ky);
    float px = dx + (float)(w - 1 + kx);
    float y0f = floorf(py), x0f = floorf(px);
    float wy = py - y0f, wx = px - x0f;
    int y0 = (int)y0f, x0 = (int)x0f;
    bool vy0 = (unsigned)y0 < 64u, vy1 = (unsigned)(y0 + 1) < 64u;
    bool vx0 = (unsigned)x0 < 64u, vx1 = (unsigned)(x0 + 1) < 64u;
    int cy0 = min(max(y0, 0), 63), cy1 = min(max(y0 + 1, 0), 63);
    int cx0 = min(max(x0, 0), 63), cx1 = min(max(x0 + 1, 0), 63);
    float mask = 1.f / (1.f + __expf(-mz));
    sw00[it] = (vy0 && vx0) ? (1.f - wy) * (1.f - wx) * mask : 0.f;
    sw01[it] = (vy0 && vx1) ? (1.f - wy) * wx * mask : 0.f;
    sw10[it] = (vy1 && vx0) ? wy * (1.f - wx) * mask : 0.f;
    sw11[it] = (vy1 && vx1) ? wy * wx * mask : 0.f;
    so00[it] = cy0 * 64 + cx0;
    so01[it] = cy0 * 64 + cx1;
    so10[it] = cy1 * 64 + cx0;
    so11[it] = cy1 * 64 + cx1;
  }
  __syncthreads();   // params visible

  // ===================== PHASE 2: main GEMM (R14 body) =====================
  const __hip_bfloat16* xb = xTh + ((size_t)b << 20);
  int vrow = tid >> 3;          // 0..31 (8 threads/row, 8 ch each)
  int chq  = tid & 7;
  int colz = (chq * 8) ^ ((vrow & 7) << 3);

  auto loadTaps = [&](int tkq, Taps& T) {
    int it = (tkq >> 2) * 32 + vrow;
    const __hip_bfloat16* base = xb + (tkq & 3) * 64 + chq * 8;
    T.t00 = *(const short8*)(base + (size_t)so00[it] * 256);
    T.t01 = *(const short8*)(base + (size_t)so01[it] * 256);
    T.t10 = *(const short8*)(base + (size_t)so10[it] * 256);
    T.t11 = *(const short8*)(base + (size_t)so11[it] * 256);
  };
  auto buildV = [&](int tkq, const Taps& T, int buf) {
    int it = (tkq >> 2) * 32 + vrow;
    float a00 = sw00[it], a01 = sw01[it], a10 = sw10[it], a11 = sw11[it];
    __hip_bfloat16 h8[8];
#pragma unroll
    for (int j = 0; j < 8; ++j) {
      float v = a00 * b2f(T.t00[j]) + a01 * b2f(T.t01[j])
              + a10 * b2f(T.t10[j]) + a11 * b2f(T.t11[j]);
      h8[j] = __float2bfloat16(v);
    }
    *(short8*)&sPV[buf][vrow * 64 + colz] = *(const short8*)h8;
  };
  auto loadW = [&](int tkq, short8 (&aw)[8]) {
#pragma unroll
    for (int fo = 0; fo < 4; ++fo)
#pragma unroll
      for (int kc = 0; kc < 2; ++kc)
        aw[fo * 2 + kc] = *(const short8*)((const char*)Wt3
                          + ((((size_t)tkq * 16 + (wv * 4 + fo)) * 2 + kc) << 10)
                          + lane * 16);
  };

  f32x4 zero4 = {0.f, 0.f, 0.f, 0.f};
  f32x4 acc[4][2];
#pragma unroll
  for (int fo = 0; fo < 4; ++fo)
#pragma unroll
    for (int fm = 0; fm < 2; ++fm) acc[fo][fm] = zero4;

  Taps TA, TB;
  short8 awA[8], awB[8];
  loadW(0, awA);
  loadTaps(0, TA);
  buildV(0, TA, 0);
  loadTaps(1, TB);
  asm volatile("s_waitcnt lgkmcnt(0)" ::: "memory");
  __builtin_amdgcn_s_barrier();

  auto body = [&](int tk, Taps& Tuse, Taps& Tload,
                  short8 (&awUse)[8], short8 (&awLoad)[8]) {
    int cb = tk & 1, nb = cb ^ 1;
    bool more1 = (tk + 1 < NKSTEP), more2 = (tk + 2 < NKSTEP);
    if (more1) loadW(tk + 1, awLoad);
    if (more2) loadTaps(tk + 2, Tload);
    if (more1) buildV(tk + 1, Tuse, nb);

    __builtin_amdgcn_s_setprio(1);
#pragma unroll
    for (int kc = 0; kc < 2; ++kc) {
      int cz = (kc * 32 + hi * 8) ^ ((lo & 7) << 3);
      short8 bv[2];
#pragma unroll
      for (int fm = 0; fm < 2; ++fm)
        bv[fm] = *(const short8*)&sPV[cb][(fm * 16 + lo) * 64 + cz];
#pragma unroll
      for (int fo = 0; fo < 4; ++fo)
#pragma unroll
        for (int fm = 0; fm < 2; ++fm)
          acc[fo][fm] = __builtin_amdgcn_mfma_f32_16x16x32_bf16(awUse[fo * 2 + kc], bv[fm], acc[fo][fm], 0, 0, 0);
    }
    __builtin_amdgcn_s_setprio(0);

    if (more1) {
      asm volatile("s_waitcnt lgkmcnt(0)" ::: "memory");
      __builtin_amdgcn_s_barrier();
    }
  };

  for (int tkp = 0; tkp < NKSTEP; tkp += 2) {
    body(tkp,     TB, TA, awA, awB);
    body(tkp + 1, TA, TB, awB, awA);
  }

  // epilogue: C layout col = lane&15 -> m, row = hi*4+r -> o
  int hwbase = m0 & 4095;
#pragma unroll
  for (int fo = 0; fo < 4; ++fo) {
    int o = wv * 64 + fo * 16 + hi * 4;
#pragma unroll
    for (int fm = 0; fm < 2; ++fm) {
      int mloc = hwbase + fm * 16 + lo;
#pragma unroll
      for (int r = 0; r < 4; ++r)
        out[((size_t)(b * 256 + o + r)) * 4096 + mloc] = acc[fo][fm][r];
    }
  }
}

// ---------------------------------------------------------------------------
extern "C" void kernel_launch(void* const* d_in, const int* in_sizes, int n_in,
                              void* d_out, int out_size, void* d_ws, size_t ws_size,
                              hipStream_t stream) {
  (void)in_sizes; (void)n_in; (void)out_size; (void)ws_size;
  const float* x     = (const float*)d_in[0];
  const float* woff  = (const float*)d_in[1];
  const float* boff  = (const float*)d_in[2];
  const float* wconv = (const float*)d_in[3];
  char* ws = (char*)d_ws;
  __hip_bfloat16* xTh  = (__hip_bfloat16*)(ws + XT_OFF);
  __hip_bfloat16* Wt3  = (__hip_bfloat16*)(ws + WT_OFF);
  __hip_bfloat16* Wot3 = (__hip_bfloat16*)(ws + WOT_OFF);
  float* out = (float*)d_out;

  hipLaunchKernelGGL(k0_wt,     dim3(2304), dim3(256), 0, stream, wconv, Wt3);
  hipLaunchKernelGGL(k0b_wot,   dim3(288),  dim3(256), 0, stream, woff, Wot3);
  hipLaunchKernelGGL(kt_xt,     dim3(1024), dim3(256), 0, stream, x, xTh);
  hipLaunchKernelGGL(k23_fused, dim3(512),  dim3(256), 0, stream, xTh, Wt3, Wot3, boff, out);
}